// Round 1
// 846.526 us; speedup vs baseline: 1.6871x; 1.6871x over previous
//
#include <hip/hip_runtime.h>

typedef __bf16 bf16;
typedef __bf16 bf16x4 __attribute__((ext_vector_type(4)));
typedef __bf16 bf16x8 __attribute__((ext_vector_type(8)));
typedef float  f32x4  __attribute__((ext_vector_type(4)));

__device__ __forceinline__ void gld16(const bf16* g, bf16* l) {
  __builtin_amdgcn_global_load_lds((const __attribute__((address_space(1))) void*)g,
                                   (__attribute__((address_space(3))) void*)l, 16, 0, 0);
}

// fp32 -> bf16 weight conversion: 4 matrices of 1M elems. grid 4096, 256 thr.
__global__ void wcvt(const float* __restrict__ w0, const float* __restrict__ w1,
                     const float* __restrict__ w2, const float* __restrict__ w3,
                     bf16* __restrict__ dst)
{
  const int m = blockIdx.x >> 10;
  const float* src = (m == 0) ? w0 : (m == 1) ? w1 : (m == 2) ? w2 : w3;
  const int i = ((blockIdx.x & 1023) * 256 + threadIdx.x) * 4;
  f32x4 v = *(const f32x4*)(src + i);
  bf16x4 o;
  #pragma unroll
  for (int j = 0; j < 4; ++j) o[j] = (bf16)v[j];
  *(bf16x4*)(dst + (size_t)m * (1024 * 1024) + i) = o;
}

// ---------------------------------------------------------------------------
// GEMM: out[m,n] = feat( sum_k A[m,k]*W[n,k] + bias[n] )
// A: fp32 (converted to bf16 during LDS staging). W: bf16 (gld16 staging).
// 128x128 tile, BK=32, 256 thr = 4 waves (2x2), m97 MFMA core.
// N is always 1024 here -> 8 col-blocks. 1-D grid, flattened:
//   - XCD-chunked swizzle (nwg % 8 == 0 always: nwg = (M/128)*8)
//   - col-fastest decode so the 8 blocks sharing an A row-panel are adjacent
//     AND on the same XCD -> A fetched ~once, W (2MB) L2-resident.
// ---------------------------------------------------------------------------
template<int FEAT, typename OutT>
__global__ __launch_bounds__(256, 2)
void gemm_af32(const float* __restrict__ A, const bf16* __restrict__ W,
               const float* __restrict__ bias, OutT* __restrict__ out,
               int M, int N, int K)
{
  __shared__ __align__(16) bf16 at[128*32];
  __shared__ __align__(16) bf16 bt[128*32];
  const int tid  = threadIdx.x;
  const int wave = tid >> 6;
  const int lane = tid & 63;
  const int quad = lane >> 4;
  const int l15  = lane & 15;

  const int q8 = gridDim.x >> 3;
  int id = blockIdx.x;
  id = (id & 7) * q8 + (id >> 3);           // XCD-chunked (gridDim.x % 8 == 0)
  const long row0 = (long)(id >> 3) * 128;  // col fastest (N==1024 -> 8 cols)
  const long col0 = (long)(id & 7) * 128;
  const int wm = wave >> 1, wn = wave & 1;

  f32x4 acc[4][4] = {};

  // A staging (fp32 -> bf16): thread t, round j: row = j*32 + (t>>3), col = (t&7)*4
  const int ar = tid >> 3;          // 0..31
  const int ac = (tid & 7) * 4;     // 0..28
  const float* Ap = A + (row0 + ar) * (long)K + ac;

  // W staging via gld16
  const int r0 = wave*16 + (lane>>2);
  const int ca = (lane&3)*8;
  const bf16* Bp0 = W + (col0 + r0      )*(long)K + ca;
  const bf16* Bp1 = W + (col0 + r0 + 64 )*(long)K + ca;
  bf16* lB0 = bt +        wave*512;
  bf16* lB1 = bt + 2048 + wave*512;

  for (int k0 = 0; k0 < K; k0 += 32) {
    __syncthreads();                       // previous readers done
    gld16(Bp0 + k0, lB0);
    gld16(Bp1 + k0, lB1);
    #pragma unroll
    for (int j = 0; j < 4; ++j) {
      f32x4 a4 = *(const f32x4*)(Ap + (long)j * 32 * K + k0);
      bf16x4 b4;
      #pragma unroll
      for (int i = 0; i < 4; ++i) b4[i] = (bf16)a4[i];
      *(bf16x4*)(at + (j*32 + ar)*32 + ac) = b4;
    }
    __syncthreads();                       // drains vmcnt + lds writes
    bf16x8 af[4], bv[4];
    #pragma unroll
    for (int t = 0; t < 4; ++t)
      af[t] = *(const bf16x8*)(at + (wm*64 + t*16 + l15)*32 + quad*8);
    #pragma unroll
    for (int t = 0; t < 4; ++t)
      bv[t] = *(const bf16x8*)(bt + (wn*64 + t*16 + l15)*32 + quad*8);
    #pragma unroll
    for (int i = 0; i < 4; ++i)
      #pragma unroll
      for (int j = 0; j < 4; ++j)
        acc[i][j] = __builtin_amdgcn_mfma_f32_16x16x32_bf16(af[i], bv[j], acc[i][j], 0, 0, 0);
  }

  #pragma unroll
  for (int i = 0; i < 4; ++i) {
    #pragma unroll
    for (int j = 0; j < 4; ++j) {
      const long col = col0 + wn*64 + j*16 + l15;
      const float bb = bias[col];
      #pragma unroll
      for (int r = 0; r < 4; ++r) {
        const long row = row0 + wm*64 + i*16 + quad*4 + r;
        float v = acc[i][j][r] + bb;
        if (FEAT) v = (v > 0.f) ? (v + 1.f) : __expf(v);   // elu(x)+1
        out[row*(long)N + col] = (OutT)v;
      }
    }
  }
}

// Same GEMM but A is bf16 (gld16 both operands) — for the output projection.
template<int FEAT, typename OutT>
__global__ __launch_bounds__(256, 2)
void gemm_abf16(const bf16* __restrict__ A, const bf16* __restrict__ W,
                const float* __restrict__ bias, OutT* __restrict__ out,
                int M, int N, int K)
{
  __shared__ __align__(16) bf16 at[128*32];
  __shared__ __align__(16) bf16 bt[128*32];
  const int tid  = threadIdx.x;
  const int wave = tid >> 6;
  const int lane = tid & 63;
  const int quad = lane >> 4;
  const int l15  = lane & 15;

  const int q8 = gridDim.x >> 3;
  int id = blockIdx.x;
  id = (id & 7) * q8 + (id >> 3);
  const long row0 = (long)(id >> 3) * 128;
  const long col0 = (long)(id & 7) * 128;
  const int wm = wave >> 1, wn = wave & 1;

  f32x4 acc[4][4] = {};

  const int r0 = wave*16 + (lane>>2);
  const int ca = (lane&3)*8;
  const bf16* Ap0 = A + (row0 + r0      )*(long)K + ca;
  const bf16* Ap1 = A + (row0 + r0 + 64 )*(long)K + ca;
  const bf16* Bp0 = W + (col0 + r0      )*(long)K + ca;
  const bf16* Bp1 = W + (col0 + r0 + 64 )*(long)K + ca;
  bf16* lA0 = at +        wave*512;
  bf16* lA1 = at + 2048 + wave*512;
  bf16* lB0 = bt +        wave*512;
  bf16* lB1 = bt + 2048 + wave*512;

  for (int k0 = 0; k0 < K; k0 += 32) {
    __syncthreads();
    gld16(Ap0 + k0, lA0);
    gld16(Ap1 + k0, lA1);
    gld16(Bp0 + k0, lB0);
    gld16(Bp1 + k0, lB1);
    __syncthreads();
    bf16x8 af[4], bv[4];
    #pragma unroll
    for (int t = 0; t < 4; ++t)
      af[t] = *(const bf16x8*)(at + (wm*64 + t*16 + l15)*32 + quad*8);
    #pragma unroll
    for (int t = 0; t < 4; ++t)
      bv[t] = *(const bf16x8*)(bt + (wn*64 + t*16 + l15)*32 + quad*8);
    #pragma unroll
    for (int i = 0; i < 4; ++i)
      #pragma unroll
      for (int j = 0; j < 4; ++j)
        acc[i][j] = __builtin_amdgcn_mfma_f32_16x16x32_bf16(af[i], bv[j], acc[i][j], 0, 0, 0);
  }

  #pragma unroll
  for (int i = 0; i < 4; ++i) {
    #pragma unroll
    for (int j = 0; j < 4; ++j) {
      const long col = col0 + wn*64 + j*16 + l15;
      const float bb = bias[col];
      #pragma unroll
      for (int r = 0; r < 4; ++r) {
        const long row = row0 + wm*64 + i*16 + quad*4 + r;
        float v = acc[i][j][r] + bb;
        if (FEAT) v = (v > 0.f) ? (v + 1.f) : __expf(v);
        out[row*(long)N + col] = (OutT)v;
      }
    }
  }
}

// ---------------------------------------------------------------------------
// kv accumulation over a K/V chunk:
//   kvacc[bh][dv][dk] += sum_s v[s][dv]*k[s][dk]  (fp32 global atomics)
//   ksum[bh][dk]      += sum_s k[s][dk]
// grid (16 heads, CR/1024), 256 thr. Block's 1024 rows always lie within one
// batch (8192 % 1024 == 0); batch index derived from global row = s_off+sbase.
// ---------------------------------------------------------------------------
__global__ __launch_bounds__(256, 2)
void kv_kernel(const bf16* __restrict__ Kc, const bf16* __restrict__ Vc,
               float* __restrict__ kvacc, float* __restrict__ ksum, int s_off)
{
  __shared__ __align__(16) bf16 kT[64*32];   // [dk][s]
  __shared__ __align__(16) bf16 vT[64*32];   // [dv][s]
  __shared__ float ksl[64];
  const int tid = threadIdx.x, wave = tid >> 6, lane = tid & 63;
  const int quad = lane >> 4, l15 = lane & 15;
  const int h = blockIdx.x;
  const long sbase = (long)blockIdx.y * 1024;
  const int b = (int)((s_off + sbase) >> 13);      // global row / 8192
  const int bh = b * 16 + h;
  const bf16* Kp = Kc + h * 64;
  const bf16* Vp = Vc + h * 64;

  if (tid < 64) ksl[tid] = 0.f;
  f32x4 acc[4] = {};
  float ks[8] = {};
  const int sld = tid >> 3;          // 0..31
  const int d0  = (tid & 7) * 8;     // 0..56

  for (int it = 0; it < 32; ++it) {
    const long s0 = sbase + it * 32;
    __syncthreads();
    bf16x8 k8 = *(const bf16x8*)(Kp + (s0 + sld) * 1024 + d0);
    bf16x8 v8 = *(const bf16x8*)(Vp + (s0 + sld) * 1024 + d0);
    #pragma unroll
    for (int i = 0; i < 8; ++i) {
      kT[(d0 + i) * 32 + sld] = k8[i];
      vT[(d0 + i) * 32 + sld] = v8[i];
      ks[i] += (float)k8[i];
    }
    __syncthreads();
    bf16x8 af = *(const bf16x8*)(vT + (wave*16 + l15)*32 + quad*8);
    #pragma unroll
    for (int tj = 0; tj < 4; ++tj) {
      bf16x8 bv = *(const bf16x8*)(kT + (tj*16 + l15)*32 + quad*8);
      acc[tj] = __builtin_amdgcn_mfma_f32_16x16x32_bf16(af, bv, acc[tj], 0, 0, 0);
    }
  }

  float* outp = kvacc + (long)bh * 4096;
  #pragma unroll
  for (int tj = 0; tj < 4; ++tj)
    #pragma unroll
    for (int r = 0; r < 4; ++r) {
      int m = wave*16 + quad*4 + r;
      int n = tj*16 + l15;
      atomicAdd(outp + m*64 + n, acc[tj][r]);
    }

  #pragma unroll
  for (int i = 0; i < 8; ++i) atomicAdd(&ksl[d0 + i], ks[i]);
  __syncthreads();
  if (tid < 64) atomicAdd(ksum + bh*64 + tid, ksl[tid]);
}

// fp32 kvacc -> bf16 kvb. grid 256, 256 thr.
__global__ void kv_pack(const float* __restrict__ kvacc, bf16* __restrict__ kvb)
{
  const int i = (blockIdx.x * 256 + threadIdx.x) * 4;
  f32x4 v = *(const f32x4*)(kvacc + i);
  #pragma unroll
  for (int j = 0; j < 4; ++j) kvb[i + j] = (bf16)v[j];
}

// ---------------------------------------------------------------------------
// attn[t][dv] = (sum_dk q[t][dk]*kv[dv][dk]) / (sum_dk q[t][dk]*ksum[dk]+EPS)
// grid (64 t-tiles, 64 bh), 256 thr. Q and attn alias (in-place safe).
// ---------------------------------------------------------------------------
__global__ __launch_bounds__(256, 2)
void attn_kernel(const bf16* Q, const bf16* __restrict__ kvb,
                 const float* __restrict__ ksum, bf16* attn)
{
  const int T = 8192;
  __shared__ __align__(16) bf16 qt[2*128*32];    // [kc][row][32]
  __shared__ __align__(16) bf16 kvt[80*72];      // rows 0..63 kv, row 64 ksum, 65..79 zero
  __shared__ float denoml[128];
  const int tid = threadIdx.x, wave = tid >> 6, lane = tid & 63;
  const int quad = lane >> 4, l15 = lane & 15;
  const int bh = blockIdx.y;
  const long t0 = (long)blockIdx.x * 128;
  const bf16* Qp = Q + ((long)(bh >> 4) * T + t0) * 1024 + (bh & 15) * 64;

  for (int c = wave; c < 16; c += 4) {
    int kc  = c >> 3;
    int row = (c & 7) * 16 + (lane >> 2);
    int col = kc * 32 + (lane & 3) * 8;
    gld16(Qp + (long)row * 1024 + col, qt + c * 512);
  }
  const bf16* kvpb = kvb + (long)bh * 4096;
  #pragma unroll
  for (int j = 0; j < 2; ++j) {
    int e = (j*256 + tid) * 8;
    int row = e >> 6, col = e & 63;
    *(bf16x8*)(kvt + row*72 + col) = *(const bf16x8*)(kvpb + e);
  }
  if (tid < 64) kvt[64*72 + tid] = (bf16)ksum[bh*64 + tid];
  if (tid < 240) {
    int row = 65 + (tid >> 4);
    int col = (tid & 15) * 4;
    #pragma unroll
    for (int i = 0; i < 4; ++i) kvt[row*72 + col + i] = (bf16)0.f;
  }
  __syncthreads();

  f32x4 acc[2][4] = {}; f32x4 accd[2] = {};
  #pragma unroll
  for (int kc = 0; kc < 2; ++kc) {
    bf16x8 af[2], bv[5];
    #pragma unroll
    for (int i = 0; i < 2; ++i)
      af[i] = *(const bf16x8*)(qt + kc*4096 + (wave*32 + i*16 + l15)*32 + quad*8);
    #pragma unroll
    for (int j = 0; j < 5; ++j)
      bv[j] = *(const bf16x8*)(kvt + (j*16 + l15)*72 + kc*32 + quad*8);
    #pragma unroll
    for (int i = 0; i < 2; ++i) {
      #pragma unroll
      for (int j = 0; j < 4; ++j)
        acc[i][j] = __builtin_amdgcn_mfma_f32_16x16x32_bf16(af[i], bv[j], acc[i][j], 0, 0, 0);
      accd[i] = __builtin_amdgcn_mfma_f32_16x16x32_bf16(af[i], bv[4], accd[i], 0, 0, 0);
    }
  }
  if (l15 == 0) {
    #pragma unroll
    for (int i = 0; i < 2; ++i)
      #pragma unroll
      for (int r = 0; r < 4; ++r)
        denoml[wave*32 + i*16 + quad*4 + r] = accd[i][r];
  }
  __syncthreads();

  bf16* ap = attn + ((long)(bh >> 4) * T + t0) * 1024 + (bh & 15) * 64;
  #pragma unroll
  for (int i = 0; i < 2; ++i)
    #pragma unroll
    for (int r = 0; r < 4; ++r) {
      int m = wave*32 + i*16 + quad*4 + r;
      float nrm = 1.f / (denoml[m] + 1e-6f);
      #pragma unroll
      for (int j = 0; j < 4; ++j)
        ap[(long)m*1024 + j*16 + l15] = (bf16)(acc[i][j][r] * nrm);
    }
}

// ---------------------------------------------------------------------------
// Workspace layout (CR chosen from ws_size, host-side, graph-safe):
//   QA    bf16[32768*1024]   64 MB  (Q projection; attn in-place)
//   Kc,Vc bf16[CR*1024]      2*CR*2KB (K/V projection staging; CR up to 32768
//                             -> single full-size chunk, no serial chunk loop)
//   Wb    bf16[4*1024*1024]   8 MB  (converted weights: q,k,v,o)
//   kvacc f32[64*4096] 1 MB;  ksum f32[4096];  kvb bf16[64*4096]
// Full path (CR=32768) needs ~211 MB; falls back 16384/8192/4096 otherwise.
// ---------------------------------------------------------------------------
extern "C" void kernel_launch(void* const* d_in, const int* in_sizes, int n_in,
                              void* d_out, int out_size, void* d_ws, size_t ws_size,
                              hipStream_t stream)
{
  const int S = 8192, D = 1024, M = 4 * S;
  const float* query = (const float*)d_in[0];
  const float* key   = (const float*)d_in[1];
  const float* value = (const float*)d_in[2];
  const float* Wq = (const float*)d_in[3];  const float* bq = (const float*)d_in[4];
  const float* Wk = (const float*)d_in[5];  const float* bk = (const float*)d_in[6];
  const float* Wv = (const float*)d_in[7];  const float* bv = (const float*)d_in[8];
  const float* Wo = (const float*)d_in[9];  const float* bo = (const float*)d_in[10];

  // pick largest chunk that fits the workspace
  const size_t fixed = (size_t)M * D * sizeof(bf16)              // QA
                     + (size_t)4 * D * D * sizeof(bf16)          // Wb
                     + (size_t)(64 * 4096 + 4096) * sizeof(float)// kvacc+ksum
                     + (size_t)64 * 4096 * sizeof(bf16);         // kvb
  int CR = 4096;
  for (int cand = 32768; cand > 4096; cand >>= 1)
    if (fixed + (size_t)2 * cand * D * sizeof(bf16) <= ws_size) { CR = cand; break; }

  bf16*  QA    = (bf16*)d_ws;
  bf16*  Kc    = QA + (size_t)M * D;
  bf16*  Vc    = Kc + (size_t)CR * D;
  bf16*  Wb    = Vc + (size_t)CR * D;
  bf16*  Wqb = Wb, *Wkb = Wb + (size_t)D*D, *Wvb = Wb + (size_t)2*D*D, *Wob = Wb + (size_t)3*D*D;
  float* kvacc = (float*)(Wb + (size_t)4 * D * D);
  float* ksum  = kvacc + 64 * 4096;
  bf16*  kvb   = (bf16*)(ksum + 4096);

  dim3 blk(256);

  wcvt<<<dim3(4096), blk, 0, stream>>>(Wq, Wk, Wv, Wo, Wb);
  hipMemsetAsync(kvacc, 0, (64 * 4096 + 4096) * sizeof(float), stream);
  gemm_af32<1, bf16><<<dim3((M/128)*8), blk, 0, stream>>>(query, Wqb, bq, QA, M, D, D);
  for (int c = 0; c < M / CR; ++c) {
    const float* krows = key   + (size_t)c * CR * D;
    const float* vrows = value + (size_t)c * CR * D;
    gemm_af32<1, bf16><<<dim3((CR/128)*8), blk, 0, stream>>>(krows, Wkb, bk, Kc, CR, D, D);
    gemm_af32<0, bf16><<<dim3((CR/128)*8), blk, 0, stream>>>(vrows, Wvb, bv, Vc, CR, D, D);
    kv_kernel<<<dim3(16, CR/1024), blk, 0, stream>>>(Kc, Vc, kvacc, ksum, c * CR);
  }
  kv_pack<<<dim3(256), blk, 0, stream>>>(kvacc, kvb);
  attn_kernel<<<dim3(S/128, 64), blk, 0, stream>>>(QA, kvb, ksum, QA);
  gemm_abf16<0, float><<<dim3((M/128)*8), blk, 0, stream>>>(QA, Wob, bo, (float*)d_out, M, D, D);
}